// Round 1
// baseline (3062.779 us; speedup 1.0000x reference)
//
#include <hip/hip_runtime.h>
#include <cstdint>

#define NN 10000
#define NE 160000
#define DD 128
#define NL 3
#define EB 32
#define AST 388   // LDS row stride for 384-wide concat tile (pad for banks, mult of 4)

__device__ __forceinline__ float wsum32(float v) {
  v += __shfl_xor(v, 1);
  v += __shfl_xor(v, 2);
  v += __shfl_xor(v, 4);
  v += __shfl_xor(v, 8);
  v += __shfl_xor(v, 16);
  return v;
}
__device__ __forceinline__ float wsum64(float v) {
  v = wsum32(v);
  v += __shfl_xor(v, 32);
  return v;
}

// ---------- input projections: out = relu(ln(inp @ W + b, g, bt)) ----------
template <int K>
__global__ __launch_bounds__(256) void k_inproj(
    const float* __restrict__ inp, const float* __restrict__ W,
    const float* __restrict__ b, const float* __restrict__ g,
    const float* __restrict__ bt, float* __restrict__ out, int rows) {
  int row = blockIdx.x * 4 + (threadIdx.x >> 6);
  if (row >= rows) return;
  int lane = threadIdx.x & 63;
  float a0 = b[lane], a1 = b[lane + 64];
#pragma unroll
  for (int k = 0; k < K; ++k) {
    float xv = inp[(size_t)row * K + k];
    a0 = fmaf(xv, W[k * DD + lane], a0);
    a1 = fmaf(xv, W[k * DD + lane + 64], a1);
  }
  float m = wsum64(a0 + a1) * (1.0f / DD);
  float q = wsum64(a0 * a0 + a1 * a1) * (1.0f / DD);
  float rstd = rsqrtf(q - m * m + 1e-5f);
  float o0 = (a0 - m) * rstd * g[lane] + bt[lane];
  float o1 = (a1 - m) * rstd * g[lane + 64] + bt[lane + 64];
  out[(size_t)row * DD + lane] = fmaxf(o0, 0.0f);
  out[(size_t)row * DD + lane + 64] = fmaxf(o1, 0.0f);
}

// ---------- per-layer edge mega-kernel ----------
// Per block: 32 edges. Stages [x_dst | x_src | e] (32x384) in LDS, then:
//  mem = relu(ln(A @ memW + b))          (stored into LDS cols 256..383)
//  delta = relu(ln(mem @ euW + b)); e = ln(e + delta)   (e updated in place)
//  logits = (x_dst@Wq . mem@Wk)/4 per head  -> lg[E,8]
//  v = mem @ Wv                           -> v[E,128]
__global__ __launch_bounds__(256) void k_edge(
    const float* __restrict__ x, float* __restrict__ e,
    const int* __restrict__ src, const int* __restrict__ dst,
    const float* __restrict__ memW, const float* __restrict__ memB,
    const float* __restrict__ memG, const float* __restrict__ memBt,
    const float* __restrict__ euW, const float* __restrict__ euB,
    const float* __restrict__ euG, const float* __restrict__ euBt,
    const float* __restrict__ enG, const float* __restrict__ enBt,
    const float* __restrict__ Wq, const float* __restrict__ Wk,
    const float* __restrict__ Wv, float* __restrict__ lg,
    float* __restrict__ v) {
  __shared__ float As[EB * AST];
  __shared__ int sD[EB], sS[EB];
  const int tid = threadIdx.x;
  const int e0 = blockIdx.x * EB;
  if (tid < EB) {
    sS[tid] = src[e0 + tid];
    sD[tid] = dst[e0 + tid];
  }
  __syncthreads();
  // stage concat tile (32 rows x 384 cols) as float4
#pragma unroll
  for (int i = 0; i < 12; ++i) {
    int f4 = i * 256 + tid;      // 0..3071
    int er = f4 / 96;            // 96 float4 per row
    int k4 = f4 - er * 96;
    const float* sp;
    if (k4 < 32)      sp = x + (size_t)sD[er] * DD + k4 * 4;
    else if (k4 < 64) sp = x + (size_t)sS[er] * DD + (k4 - 32) * 4;
    else              sp = e + (size_t)(e0 + er) * DD + (k4 - 64) * 4;
    *(float4*)(As + er * AST + k4 * 4) = *(const float4*)sp;
  }
  __syncthreads();

  const int c = tid & 31;   // col group (4 cols)
  const int rg = tid >> 5;  // 8 row groups x 4 edges
  const int eb = rg * 4;
  const int col = c * 4;

  // ---- GEMM1: mem = relu(ln(A @ memW + memB)) ----
  float acc[4][4];
#pragma unroll
  for (int j = 0; j < 4; ++j)
#pragma unroll
    for (int i = 0; i < 4; ++i) acc[j][i] = 0.0f;
#pragma unroll 4
  for (int k = 0; k < 384; ++k) {
    float4 w = *(const float4*)(memW + k * DD + col);
#pragma unroll
    for (int j = 0; j < 4; ++j) {
      float a = As[(eb + j) * AST + k];
      acc[j][0] = fmaf(a, w.x, acc[j][0]);
      acc[j][1] = fmaf(a, w.y, acc[j][1]);
      acc[j][2] = fmaf(a, w.z, acc[j][2]);
      acc[j][3] = fmaf(a, w.w, acc[j][3]);
    }
  }
  float4 bi = *(const float4*)(memB + col);
  float4 gm = *(const float4*)(memG + col);
  float4 bm = *(const float4*)(memBt + col);
  float mv[4][4];
#pragma unroll
  for (int j = 0; j < 4; ++j) {
    float t0 = acc[j][0] + bi.x, t1 = acc[j][1] + bi.y;
    float t2 = acc[j][2] + bi.z, t3 = acc[j][3] + bi.w;
    float m = wsum32(t0 + t1 + t2 + t3) * (1.0f / DD);
    float q = wsum32(t0 * t0 + t1 * t1 + t2 * t2 + t3 * t3) * (1.0f / DD);
    float rstd = rsqrtf(q - m * m + 1e-5f);
    mv[j][0] = fmaxf((t0 - m) * rstd * gm.x + bm.x, 0.0f);
    mv[j][1] = fmaxf((t1 - m) * rstd * gm.y + bm.y, 0.0f);
    mv[j][2] = fmaxf((t2 - m) * rstd * gm.z + bm.z, 0.0f);
    mv[j][3] = fmaxf((t3 - m) * rstd * gm.w + bm.w, 0.0f);
  }
  __syncthreads();  // everyone done reading e-part of As
  // store mem tile over the e-part (cols 256..383)
#pragma unroll
  for (int j = 0; j < 4; ++j)
    *(float4*)(As + (eb + j) * AST + 256 + col) =
        make_float4(mv[j][0], mv[j][1], mv[j][2], mv[j][3]);
  __syncthreads();

  // ---- GEMM2: delta = relu(ln(mem @ euW + euB)); e = ln(e + delta) ----
#pragma unroll
  for (int j = 0; j < 4; ++j)
#pragma unroll
    for (int i = 0; i < 4; ++i) acc[j][i] = 0.0f;
#pragma unroll 4
  for (int k = 0; k < 128; ++k) {
    float4 w = *(const float4*)(euW + k * DD + col);
#pragma unroll
    for (int j = 0; j < 4; ++j) {
      float a = As[(eb + j) * AST + 256 + k];
      acc[j][0] = fmaf(a, w.x, acc[j][0]);
      acc[j][1] = fmaf(a, w.y, acc[j][1]);
      acc[j][2] = fmaf(a, w.z, acc[j][2]);
      acc[j][3] = fmaf(a, w.w, acc[j][3]);
    }
  }
  {
    float4 beu = *(const float4*)(euB + col);
    float4 geu = *(const float4*)(euG + col);
    float4 teu = *(const float4*)(euBt + col);
    float4 gen = *(const float4*)(enG + col);
    float4 ten = *(const float4*)(enBt + col);
#pragma unroll
    for (int j = 0; j < 4; ++j) {
      float t0 = acc[j][0] + beu.x, t1 = acc[j][1] + beu.y;
      float t2 = acc[j][2] + beu.z, t3 = acc[j][3] + beu.w;
      float m = wsum32(t0 + t1 + t2 + t3) * (1.0f / DD);
      float q = wsum32(t0 * t0 + t1 * t1 + t2 * t2 + t3 * t3) * (1.0f / DD);
      float rstd = rsqrtf(q - m * m + 1e-5f);
      float d0 = fmaxf((t0 - m) * rstd * geu.x + teu.x, 0.0f);
      float d1 = fmaxf((t1 - m) * rstd * geu.y + teu.y, 0.0f);
      float d2 = fmaxf((t2 - m) * rstd * geu.z + teu.z, 0.0f);
      float d3 = fmaxf((t3 - m) * rstd * geu.w + teu.w, 0.0f);
      float4 eo = *(const float4*)(e + (size_t)(e0 + eb + j) * DD + col);
      float p0 = eo.x + d0, p1 = eo.y + d1, p2 = eo.z + d2, p3 = eo.w + d3;
      float m2 = wsum32(p0 + p1 + p2 + p3) * (1.0f / DD);
      float q2 = wsum32(p0 * p0 + p1 * p1 + p2 * p2 + p3 * p3) * (1.0f / DD);
      float r2 = rsqrtf(q2 - m2 * m2 + 1e-5f);
      float4 eo2;
      eo2.x = (p0 - m2) * r2 * gen.x + ten.x;
      eo2.y = (p1 - m2) * r2 * gen.y + ten.y;
      eo2.z = (p2 - m2) * r2 * gen.z + ten.z;
      eo2.w = (p3 - m2) * r2 * gen.w + ten.w;
      *(float4*)(e + (size_t)(e0 + eb + j) * DD + col) = eo2;
    }
  }

  // ---- GEMM3/4: q = x_dst @ Wq, k = mem @ Wk; logits per head ----
  float qa[4][4], ka[4][4];
#pragma unroll
  for (int j = 0; j < 4; ++j)
#pragma unroll
    for (int i = 0; i < 4; ++i) { qa[j][i] = 0.0f; ka[j][i] = 0.0f; }
#pragma unroll 2
  for (int k = 0; k < 128; ++k) {
    float4 wq = *(const float4*)(Wq + k * DD + col);
    float4 wk = *(const float4*)(Wk + k * DD + col);
#pragma unroll
    for (int j = 0; j < 4; ++j) {
      float ax = As[(eb + j) * AST + k];
      float am = As[(eb + j) * AST + 256 + k];
      qa[j][0] = fmaf(ax, wq.x, qa[j][0]);
      qa[j][1] = fmaf(ax, wq.y, qa[j][1]);
      qa[j][2] = fmaf(ax, wq.z, qa[j][2]);
      qa[j][3] = fmaf(ax, wq.w, qa[j][3]);
      ka[j][0] = fmaf(am, wk.x, ka[j][0]);
      ka[j][1] = fmaf(am, wk.y, ka[j][1]);
      ka[j][2] = fmaf(am, wk.z, ka[j][2]);
      ka[j][3] = fmaf(am, wk.w, ka[j][3]);
    }
  }
#pragma unroll
  for (int j = 0; j < 4; ++j) {
    float p = qa[j][0] * ka[j][0] + qa[j][1] * ka[j][1] +
              qa[j][2] * ka[j][2] + qa[j][3] * ka[j][3];
    p += __shfl_xor(p, 1);
    p += __shfl_xor(p, 2);
    if ((c & 3) == 0) lg[(size_t)(e0 + eb + j) * 8 + (c >> 2)] = p * 0.25f;
  }

  // ---- GEMM5: v = mem @ Wv ----
  float va[4][4];
#pragma unroll
  for (int j = 0; j < 4; ++j)
#pragma unroll
    for (int i = 0; i < 4; ++i) va[j][i] = 0.0f;
#pragma unroll 4
  for (int k = 0; k < 128; ++k) {
    float4 w = *(const float4*)(Wv + k * DD + col);
#pragma unroll
    for (int j = 0; j < 4; ++j) {
      float a = As[(eb + j) * AST + 256 + k];
      va[j][0] = fmaf(a, w.x, va[j][0]);
      va[j][1] = fmaf(a, w.y, va[j][1]);
      va[j][2] = fmaf(a, w.z, va[j][2]);
      va[j][3] = fmaf(a, w.w, va[j][3]);
    }
  }
#pragma unroll
  for (int j = 0; j < 4; ++j)
    *(float4*)(v + (size_t)(e0 + eb + j) * DD + col) =
        make_float4(va[j][0], va[j][1], va[j][2], va[j][3]);
}

// ---------- segment softmax ----------
__global__ __launch_bounds__(256) void k_segmax(
    const float* __restrict__ lg, const int* __restrict__ dst,
    unsigned* __restrict__ nmax) {
  int idx = blockIdx.x * 256 + threadIdx.x;  // < E*8
  int e = idx >> 3, h = idx & 7;
  float f = lg[idx];
  unsigned u = __float_as_uint(f);
  u = (u & 0x80000000u) ? ~u : (u | 0x80000000u);
  atomicMax(&nmax[dst[e] * 8 + h], u);
}

__global__ __launch_bounds__(256) void k_segexp(
    float* __restrict__ lg, const int* __restrict__ dst,
    const unsigned* __restrict__ nmax, float* __restrict__ nsum) {
  int idx = blockIdx.x * 256 + threadIdx.x;
  int e = idx >> 3, h = idx & 7;
  unsigned u = nmax[dst[e] * 8 + h];
  u = (u & 0x80000000u) ? (u ^ 0x80000000u) : ~u;
  float mx = __uint_as_float(u);
  float ex = expf(lg[idx] - mx);
  lg[idx] = ex;
  atomicAdd(&nsum[dst[e] * 8 + h], ex);
}

// ---------- attention aggregation: agg[dst] += (attn*v) @ Wo ----------
__global__ __launch_bounds__(256) void k_attn(
    const float* __restrict__ v, const float* __restrict__ ex,
    const float* __restrict__ nsum, const int* __restrict__ dst,
    const float* __restrict__ Wo, float* __restrict__ agg) {
  __shared__ float Vs[EB * 132];
  __shared__ float attnS[EB * 8];
  __shared__ int sD[EB];
  const int tid = threadIdx.x;
  const int e0 = blockIdx.x * EB;
  if (tid < EB) sD[tid] = dst[e0 + tid];
  __syncthreads();
  {
    int er = tid >> 3, h = tid & 7;
    attnS[er * 8 + h] =
        ex[(size_t)(e0 + er) * 8 + h] / (nsum[sD[er] * 8 + h] + 1e-16f);
  }
  __syncthreads();
#pragma unroll
  for (int i = 0; i < 4; ++i) {
    int f4 = i * 256 + tid;
    int er = f4 >> 5, k4 = f4 & 31;
    float4 vv = *(const float4*)(v + (size_t)(e0 + er) * DD + k4 * 4);
    float a = attnS[er * 8 + (k4 >> 2)];
    vv.x *= a; vv.y *= a; vv.z *= a; vv.w *= a;
    *(float4*)(Vs + er * 132 + k4 * 4) = vv;
  }
  __syncthreads();
  const int c = tid & 31, rg = tid >> 5;
  const int eb = rg * 4, col = c * 4;
  float acc[4][4];
#pragma unroll
  for (int j = 0; j < 4; ++j)
#pragma unroll
    for (int i = 0; i < 4; ++i) acc[j][i] = 0.0f;
#pragma unroll 4
  for (int k = 0; k < 128; ++k) {
    float4 w = *(const float4*)(Wo + k * DD + col);
#pragma unroll
    for (int j = 0; j < 4; ++j) {
      float a = Vs[(eb + j) * 132 + k];
      acc[j][0] = fmaf(a, w.x, acc[j][0]);
      acc[j][1] = fmaf(a, w.y, acc[j][1]);
      acc[j][2] = fmaf(a, w.z, acc[j][2]);
      acc[j][3] = fmaf(a, w.w, acc[j][3]);
    }
  }
#pragma unroll
  for (int j = 0; j < 4; ++j) {
    float* base = agg + (size_t)sD[eb + j] * DD + col;
    atomicAdd(base + 0, acc[j][0]);
    atomicAdd(base + 1, acc[j][1]);
    atomicAdd(base + 2, acc[j][2]);
    atomicAdd(base + 3, acc[j][3]);
  }
}

// ---------- x = ln(x + agg, g, bt) ----------
__global__ __launch_bounds__(256) void k_nodeln(
    float* __restrict__ x, const float* __restrict__ agg,
    const float* __restrict__ g, const float* __restrict__ bt) {
  int row = blockIdx.x * 4 + (threadIdx.x >> 6);
  int lane = threadIdx.x & 63;
  size_t base = (size_t)row * DD;
  float a0 = x[base + lane] + agg[base + lane];
  float a1 = x[base + lane + 64] + agg[base + lane + 64];
  float m = wsum64(a0 + a1) * (1.0f / DD);
  float q = wsum64(a0 * a0 + a1 * a1) * (1.0f / DD);
  float rstd = rsqrtf(q - m * m + 1e-5f);
  x[base + lane] = (a0 - m) * rstd * g[lane] + bt[lane];
  x[base + lane + 64] = (a1 - m) * rstd * g[lane + 64] + bt[lane + 64];
}

// ---------- FFN ----------
__global__ __launch_bounds__(256) void k_ffn1(
    const float* __restrict__ x, const float* __restrict__ W1,
    const float* __restrict__ b1, float* __restrict__ h) {
  __shared__ float Xs[16 * 132];
  const int tid = threadIdx.x;
  const int r0 = blockIdx.x * 16;
#pragma unroll
  for (int i = 0; i < 2; ++i) {
    int f4 = i * 256 + tid;
    int r = f4 >> 5, k4 = f4 & 31;
    *(float4*)(Xs + r * 132 + k4 * 4) =
        *(const float4*)(x + (size_t)(r0 + r) * DD + k4 * 4);
  }
  __syncthreads();
  const int c = tid & 63, rg = tid >> 6;
  const int col = c * 4, rb = rg * 4;
  float acc[4][4];
#pragma unroll
  for (int j = 0; j < 4; ++j)
#pragma unroll
    for (int i = 0; i < 4; ++i) acc[j][i] = 0.0f;
#pragma unroll 4
  for (int k = 0; k < 128; ++k) {
    float4 w = *(const float4*)(W1 + k * 256 + col);
#pragma unroll
    for (int j = 0; j < 4; ++j) {
      float a = Xs[(rb + j) * 132 + k];
      acc[j][0] = fmaf(a, w.x, acc[j][0]);
      acc[j][1] = fmaf(a, w.y, acc[j][1]);
      acc[j][2] = fmaf(a, w.z, acc[j][2]);
      acc[j][3] = fmaf(a, w.w, acc[j][3]);
    }
  }
  float4 b = *(const float4*)(b1 + col);
#pragma unroll
  for (int j = 0; j < 4; ++j) {
    float4 o;
    o.x = fmaxf(acc[j][0] + b.x, 0.0f);
    o.y = fmaxf(acc[j][1] + b.y, 0.0f);
    o.z = fmaxf(acc[j][2] + b.z, 0.0f);
    o.w = fmaxf(acc[j][3] + b.w, 0.0f);
    *(float4*)(h + (size_t)(r0 + rb + j) * 256 + col) = o;
  }
}

__global__ __launch_bounds__(256) void k_ffn2(
    const float* __restrict__ x, const float* __restrict__ hb,
    const float* __restrict__ W2, const float* __restrict__ b2,
    const float* __restrict__ g, const float* __restrict__ bt,
    float* __restrict__ out) {
  __shared__ float Hs[16 * 260];
  const int tid = threadIdx.x;
  const int r0 = blockIdx.x * 16;
#pragma unroll
  for (int i = 0; i < 4; ++i) {
    int f4 = i * 256 + tid;
    int r = f4 >> 6, k4 = f4 & 63;
    *(float4*)(Hs + r * 260 + k4 * 4) =
        *(const float4*)(hb + (size_t)(r0 + r) * 256 + k4 * 4);
  }
  __syncthreads();
  const int c = tid & 31, rg = tid >> 5;
  const int col = c * 4, rb = rg * 2;
  float acc[2][4];
#pragma unroll
  for (int j = 0; j < 2; ++j)
#pragma unroll
    for (int i = 0; i < 4; ++i) acc[j][i] = 0.0f;
#pragma unroll 4
  for (int k = 0; k < 256; ++k) {
    float4 w = *(const float4*)(W2 + k * DD + col);
#pragma unroll
    for (int j = 0; j < 2; ++j) {
      float a = Hs[(rb + j) * 260 + k];
      acc[j][0] = fmaf(a, w.x, acc[j][0]);
      acc[j][1] = fmaf(a, w.y, acc[j][1]);
      acc[j][2] = fmaf(a, w.z, acc[j][2]);
      acc[j][3] = fmaf(a, w.w, acc[j][3]);
    }
  }
  float4 b = *(const float4*)(b2 + col);
  float4 gg = *(const float4*)(g + col);
  float4 tt = *(const float4*)(bt + col);
#pragma unroll
  for (int j = 0; j < 2; ++j) {
    float4 xo = *(const float4*)(x + (size_t)(r0 + rb + j) * DD + col);
    float t0 = acc[j][0] + b.x + xo.x, t1 = acc[j][1] + b.y + xo.y;
    float t2 = acc[j][2] + b.z + xo.z, t3 = acc[j][3] + b.w + xo.w;
    float m = wsum32(t0 + t1 + t2 + t3) * (1.0f / DD);
    float q = wsum32(t0 * t0 + t1 * t1 + t2 * t2 + t3 * t3) * (1.0f / DD);
    float rstd = rsqrtf(q - m * m + 1e-5f);
    float4 o;
    o.x = (t0 - m) * rstd * gg.x + tt.x;
    o.y = (t1 - m) * rstd * gg.y + tt.y;
    o.z = (t2 - m) * rstd * gg.z + tt.z;
    o.w = (t3 - m) * rstd * gg.w + tt.w;
    *(float4*)(out + (size_t)(r0 + rb + j) * DD + col) = o;
  }
}

extern "C" void kernel_launch(void* const* d_in, const int* in_sizes, int n_in,
                              void* d_out, int out_size, void* d_ws,
                              size_t ws_size, hipStream_t stream) {
  (void)in_sizes; (void)n_in; (void)out_size; (void)ws_size;
  const float* lane_feats = (const float*)d_in[0];
  const float* edge_attrs = (const float*)d_in[1];
  const int* ei = (const int*)d_in[2];
  const int* src = ei;
  const int* dst = ei + NE;
  const float* node_W = (const float*)d_in[3];
  const float* node_b = (const float*)d_in[4];
  const float* node_g = (const float*)d_in[5];
  const float* node_bt = (const float*)d_in[6];
  const float* rpe_W = (const float*)d_in[7];
  const float* rpe_b = (const float*)d_in[8];
  const float* rpe_g = (const float*)d_in[9];
  const float* rpe_bt = (const float*)d_in[10];
  const float* mem_W = (const float*)d_in[11];
  const float* mem_b = (const float*)d_in[12];
  const float* mem_g = (const float*)d_in[13];
  const float* mem_bt = (const float*)d_in[14];
  const float* Wq = (const float*)d_in[15];
  const float* Wk = (const float*)d_in[16];
  const float* Wv = (const float*)d_in[17];
  const float* Wo = (const float*)d_in[18];
  const float* eu_W = (const float*)d_in[19];
  const float* eu_b = (const float*)d_in[20];
  const float* eu_g = (const float*)d_in[21];
  const float* eu_bt = (const float*)d_in[22];
  const float* en_g = (const float*)d_in[23];
  const float* en_bt = (const float*)d_in[24];
  const float* ffn_W1 = (const float*)d_in[25];
  const float* ffn_b1 = (const float*)d_in[26];
  const float* ffn_W2 = (const float*)d_in[27];
  const float* ffn_b2 = (const float*)d_in[28];
  const float* n1_g = (const float*)d_in[29];
  const float* n1_bt = (const float*)d_in[30];
  const float* n2_g = (const float*)d_in[31];
  const float* n2_bt = (const float*)d_in[32];

  float* ws = (float*)d_ws;
  float* x = ws;                          // N*128
  float* e = x + (size_t)NN * DD;         // E*128
  float* v = e + (size_t)NE * DD;         // E*128
  float* lg = v + (size_t)NE * DD;        // E*8
  float* agg = lg + (size_t)NE * 8;       // N*128
  float* nmaxF = agg + (size_t)NN * DD;   // N*8 (unsigned keys)
  float* nsum = nmaxF + (size_t)NN * 8;   // N*8
  float* hbuf = nsum + (size_t)NN * 8;    // N*256

  // input projections
  k_inproj<10><<<NN / 4, 256, 0, stream>>>(lane_feats, node_W, node_b, node_g,
                                           node_bt, x, NN);
  k_inproj<9><<<NE / 4, 256, 0, stream>>>(edge_attrs, rpe_W, rpe_b, rpe_g,
                                          rpe_bt, e, NE);

  for (int l = 0; l < NL; ++l) {
    // zero agg + nmax + nsum (contiguous)
    hipMemsetAsync(agg, 0, (size_t)(NN * DD + 2 * NN * 8) * sizeof(float),
                   stream);
    k_edge<<<NE / EB, 256, 0, stream>>>(
        x, e, src, dst, mem_W + (size_t)l * 384 * DD, mem_b + l * DD,
        mem_g + l * DD, mem_bt + l * DD, eu_W + (size_t)l * DD * DD,
        eu_b + l * DD, eu_g + l * DD, eu_bt + l * DD, en_g + l * DD,
        en_bt + l * DD, Wq + (size_t)l * DD * DD, Wk + (size_t)l * DD * DD,
        Wv + (size_t)l * DD * DD, lg, v);
    k_segmax<<<NE * 8 / 256, 256, 0, stream>>>(lg, dst, (unsigned*)nmaxF);
    k_segexp<<<NE * 8 / 256, 256, 0, stream>>>(lg, dst,
                                               (const unsigned*)nmaxF, nsum);
    k_attn<<<NE / EB, 256, 0, stream>>>(v, lg, nsum, dst,
                                        Wo + (size_t)l * DD * DD, agg);
    k_nodeln<<<NN / 4, 256, 0, stream>>>(x, agg, n1_g + l * DD,
                                         n1_bt + l * DD);
    k_ffn1<<<NN / 16, 256, 0, stream>>>(x, ffn_W1 + (size_t)l * DD * 256,
                                        ffn_b1 + l * 256, hbuf);
    k_ffn2<<<NN / 16, 256, 0, stream>>>(
        x, hbuf, ffn_W2 + (size_t)l * 256 * DD, ffn_b2 + l * DD,
        n2_g + l * DD, n2_bt + l * DD, (l == NL - 1) ? (float*)d_out : x);
  }
}

// Round 2
// 1415.804 us; speedup vs baseline: 2.1633x; 2.1633x over previous
//
#include <hip/hip_runtime.h>
#include <cstdint>

#define NN 10000
#define NE 160000
#define DD 128
#define NL 3
#define AST2 392  // LDS row stride in ushorts for 64x384 concat tile (16B-aligned)

typedef __attribute__((ext_vector_type(8))) __bf16 bf16x8;
typedef __attribute__((ext_vector_type(4))) float f32x4;

__device__ __forceinline__ ushort f2bf(float f) {
  unsigned u = __float_as_uint(f);
  return (ushort)((u + 0x7fffu + ((u >> 16) & 1u)) >> 16);
}
__device__ __forceinline__ float bf2f(ushort s) {
  return __uint_as_float(((unsigned)s) << 16);
}
__device__ __forceinline__ float wsum32(float v) {
  v += __shfl_xor(v, 1); v += __shfl_xor(v, 2); v += __shfl_xor(v, 4);
  v += __shfl_xor(v, 8); v += __shfl_xor(v, 16);
  return v;
}
__device__ __forceinline__ float wsum64(float v) {
  v = wsum32(v); v += __shfl_xor(v, 32); return v;
}
__device__ __forceinline__ void red16_2(float& a, float& b) {
#pragma unroll
  for (int m = 1; m < 16; m <<= 1) { a += __shfl_xor(a, m); b += __shfl_xor(b, m); }
}

// ---------- transpose fp32 [K][N] -> bf16 [N][K], batched over z ----------
__global__ __launch_bounds__(256) void k_transp(const float* __restrict__ in,
                                                ushort* __restrict__ out,
                                                int K, int N) {
  __shared__ float T[32][33];
  int k0 = blockIdx.x * 32, n0 = blockIdx.y * 32;
  in += (size_t)blockIdx.z * K * N;
  out += (size_t)blockIdx.z * K * N;
  int tx = threadIdx.x & 31, ty = threadIdx.x >> 5;
#pragma unroll
  for (int r = 0; r < 32; r += 8)
    if (k0 + ty + r < K && n0 + tx < N)
      T[ty + r][tx] = in[(size_t)(k0 + ty + r) * N + n0 + tx];
  __syncthreads();
#pragma unroll
  for (int r = 0; r < 32; r += 8)
    if (n0 + ty + r < N && k0 + tx < K)
      out[(size_t)(n0 + ty + r) * K + k0 + tx] = f2bf(T[tx][ty + r]);
}

// ---------- input projections: relu(ln(inp @ W + b)) -> fp32 (opt) + bf16 ----------
template <int K>
__global__ __launch_bounds__(256) void k_inproj(
    const float* __restrict__ inp, const float* __restrict__ W,
    const float* __restrict__ b, const float* __restrict__ g,
    const float* __restrict__ bt, float* __restrict__ outF,
    ushort* __restrict__ outB, int rows) {
  int row = blockIdx.x * 4 + (threadIdx.x >> 6);
  if (row >= rows) return;
  int lane = threadIdx.x & 63;
  float a0 = b[lane], a1 = b[lane + 64];
#pragma unroll
  for (int k = 0; k < K; ++k) {
    float xv = inp[(size_t)row * K + k];
    a0 = fmaf(xv, W[k * DD + lane], a0);
    a1 = fmaf(xv, W[k * DD + lane + 64], a1);
  }
  float m = wsum64(a0 + a1) * (1.0f / DD);
  float q = wsum64(a0 * a0 + a1 * a1) * (1.0f / DD);
  float rstd = rsqrtf(q - m * m + 1e-5f);
  float o0 = fmaxf((a0 - m) * rstd * g[lane] + bt[lane], 0.0f);
  float o1 = fmaxf((a1 - m) * rstd * g[lane + 64] + bt[lane + 64], 0.0f);
  size_t base = (size_t)row * DD;
  if (outF) { outF[base + lane] = o0; outF[base + lane + 64] = o1; }
  outB[base + lane] = f2bf(o0);
  outB[base + lane + 64] = f2bf(o1);
}

// ---------- per-layer edge mega-kernel (MFMA bf16) ----------
// 64 edges/block, 4 waves; wave w owns rows w*16..w*16+15.
// LDS As cols: [0..127]=x_dst  [128..255]=x_src -> mem -> v  [256..383]=e -> e_new
__global__ __launch_bounds__(256) void k_edge(
    const ushort* __restrict__ xb, ushort* __restrict__ eb,
    ushort* __restrict__ vb, const int* __restrict__ src,
    const int* __restrict__ dst, const ushort* __restrict__ memWT,
    const float* __restrict__ memB, const float* __restrict__ memG,
    const float* __restrict__ memBt, const ushort* __restrict__ euWT,
    const float* __restrict__ euB, const float* __restrict__ euG,
    const float* __restrict__ euBt, const float* __restrict__ enG,
    const float* __restrict__ enBt, const ushort* __restrict__ WqT,
    const ushort* __restrict__ WkT, const ushort* __restrict__ WvT,
    float* __restrict__ lg) {
  __shared__ __align__(16) ushort As[64 * AST2];
  __shared__ int sD[64], sS[64];
  const int tid = threadIdx.x;
  const int e0 = blockIdx.x * 64;
  if (tid < 64) { sS[tid] = src[e0 + tid]; sD[tid] = dst[e0 + tid]; }
  __syncthreads();
#pragma unroll
  for (int it = 0; it < 12; ++it) {
    int ch = it * 256 + tid;         // 3072 chunks of 16B
    int row = ch / 48, j = ch % 48;  // 48 chunks per row
    const ushort* sp;
    if (j < 16)       sp = xb + (size_t)sD[row] * DD + j * 8;
    else if (j < 32)  sp = xb + (size_t)sS[row] * DD + (j - 16) * 8;
    else              sp = eb + (size_t)(e0 + row) * DD + (j - 32) * 8;
    *(uint4*)(As + row * AST2 + j * 8) = *(const uint4*)sp;
  }
  __syncthreads();

  const int lane = tid & 63;
  const int wv = tid >> 6;
  const int c = lane & 15, g = lane >> 4;
  const int r0 = wv * 16;
  const ushort* Arow = As + (r0 + c) * AST2;  // this lane's A-frag row

  // ---- GEMM1: mem = relu(ln(A[0..383] @ memW + memB)) ----
  f32x4 acc[8];
#pragma unroll
  for (int t = 0; t < 8; ++t) acc[t] = (f32x4){0.f, 0.f, 0.f, 0.f};
#pragma unroll
  for (int kk = 0; kk < 12; ++kk) {
    bf16x8 a = *(const bf16x8*)(Arow + kk * 32 + g * 8);
#pragma unroll
    for (int t = 0; t < 8; ++t) {
      bf16x8 b = *(const bf16x8*)(memWT + (size_t)(t * 16 + c) * 384 + kk * 32 + g * 8);
      acc[t] = __builtin_amdgcn_mfma_f32_16x16x32_bf16(a, b, acc[t], 0, 0, 0);
    }
  }
  {
    float s1[4] = {0, 0, 0, 0}, s2[4] = {0, 0, 0, 0};
#pragma unroll
    for (int t = 0; t < 8; ++t) {
      float bv = memB[t * 16 + c];
#pragma unroll
      for (int rr = 0; rr < 4; ++rr) {
        float v = acc[t][rr] + bv;
        acc[t][rr] = v; s1[rr] += v; s2[rr] += v * v;
      }
    }
    float mean[4], rstd[4];
#pragma unroll
    for (int rr = 0; rr < 4; ++rr) {
      red16_2(s1[rr], s2[rr]);
      mean[rr] = s1[rr] * (1.f / DD);
      rstd[rr] = rsqrtf(s2[rr] * (1.f / DD) - mean[rr] * mean[rr] + 1e-5f);
    }
#pragma unroll
    for (int t = 0; t < 8; ++t) {
      float gv = memG[t * 16 + c], tv = memBt[t * 16 + c];
#pragma unroll
      for (int rr = 0; rr < 4; ++rr) {
        float o = fmaxf((acc[t][rr] - mean[rr]) * rstd[rr] * gv + tv, 0.f);
        As[(r0 + g * 4 + rr) * AST2 + 128 + t * 16 + c] = f2bf(o);  // mem over x_src
      }
    }
  }

  // ---- GEMM q (A = x_dst) and k (A = mem), combined k-loop ----
  f32x4 qa[8], ka[8];
#pragma unroll
  for (int t = 0; t < 8; ++t) { qa[t] = (f32x4){0.f,0.f,0.f,0.f}; ka[t] = (f32x4){0.f,0.f,0.f,0.f}; }
#pragma unroll
  for (int kk = 0; kk < 4; ++kk) {
    bf16x8 ax = *(const bf16x8*)(Arow + kk * 32 + g * 8);
    bf16x8 am = *(const bf16x8*)(Arow + 128 + kk * 32 + g * 8);
#pragma unroll
    for (int t = 0; t < 8; ++t) {
      bf16x8 bq = *(const bf16x8*)(WqT + (size_t)(t * 16 + c) * 128 + kk * 32 + g * 8);
      bf16x8 bk = *(const bf16x8*)(WkT + (size_t)(t * 16 + c) * 128 + kk * 32 + g * 8);
      qa[t] = __builtin_amdgcn_mfma_f32_16x16x32_bf16(ax, bq, qa[t], 0, 0, 0);
      ka[t] = __builtin_amdgcn_mfma_f32_16x16x32_bf16(am, bk, ka[t], 0, 0, 0);
    }
  }
  // logits[row][h]: head h == col-tile t; reduce q*k over the 16 cols (lanes)
#pragma unroll
  for (int t = 0; t < 8; ++t) {
    float p[4];
#pragma unroll
    for (int rr = 0; rr < 4; ++rr) p[rr] = qa[t][rr] * ka[t][rr];
#pragma unroll
    for (int m = 1; m < 16; m <<= 1)
#pragma unroll
      for (int rr = 0; rr < 4; ++rr) p[rr] += __shfl_xor(p[rr], m);
    if (c == t) {
#pragma unroll
      for (int rr = 0; rr < 4; ++rr)
        lg[(size_t)(e0 + r0 + g * 4 + rr) * 8 + t] = p[rr] * 0.25f;
    }
  }

  // ---- GEMM2: delta = relu(ln(mem @ euW + euB)); e = ln(e + delta) ----
#pragma unroll
  for (int t = 0; t < 8; ++t) acc[t] = (f32x4){0.f, 0.f, 0.f, 0.f};
#pragma unroll
  for (int kk = 0; kk < 4; ++kk) {
    bf16x8 am = *(const bf16x8*)(Arow + 128 + kk * 32 + g * 8);
#pragma unroll
    for (int t = 0; t < 8; ++t) {
      bf16x8 b = *(const bf16x8*)(euWT + (size_t)(t * 16 + c) * 128 + kk * 32 + g * 8);
      acc[t] = __builtin_amdgcn_mfma_f32_16x16x32_bf16(am, b, acc[t], 0, 0, 0);
    }
  }
  {
    float s1[4] = {0, 0, 0, 0}, s2[4] = {0, 0, 0, 0};
#pragma unroll
    for (int t = 0; t < 8; ++t) {
      float bv = euB[t * 16 + c];
#pragma unroll
      for (int rr = 0; rr < 4; ++rr) {
        float v = acc[t][rr] + bv;
        acc[t][rr] = v; s1[rr] += v; s2[rr] += v * v;
      }
    }
    float mean[4], rstd[4];
#pragma unroll
    for (int rr = 0; rr < 4; ++rr) {
      red16_2(s1[rr], s2[rr]);
      mean[rr] = s1[rr] * (1.f / DD);
      rstd[rr] = rsqrtf(s2[rr] * (1.f / DD) - mean[rr] * mean[rr] + 1e-5f);
    }
    float t1[4] = {0, 0, 0, 0}, t2[4] = {0, 0, 0, 0};
#pragma unroll
    for (int t = 0; t < 8; ++t) {
      float gv = euG[t * 16 + c], tv = euBt[t * 16 + c];
#pragma unroll
      for (int rr = 0; rr < 4; ++rr) {
        float d = fmaxf((acc[t][rr] - mean[rr]) * rstd[rr] * gv + tv, 0.f);
        float eo = bf2f(As[(r0 + g * 4 + rr) * AST2 + 256 + t * 16 + c]);
        float pv = eo + d;
        acc[t][rr] = pv; t1[rr] += pv; t2[rr] += pv * pv;
      }
    }
    float mean3[4], rstd3[4];
#pragma unroll
    for (int rr = 0; rr < 4; ++rr) {
      red16_2(t1[rr], t2[rr]);
      mean3[rr] = t1[rr] * (1.f / DD);
      rstd3[rr] = rsqrtf(t2[rr] * (1.f / DD) - mean3[rr] * mean3[rr] + 1e-5f);
    }
#pragma unroll
    for (int t = 0; t < 8; ++t) {
      float gv = enG[t * 16 + c], tv = enBt[t * 16 + c];
#pragma unroll
      for (int rr = 0; rr < 4; ++rr) {
        float en = (acc[t][rr] - mean3[rr]) * rstd3[rr] * gv + tv;
        As[(r0 + g * 4 + rr) * AST2 + 256 + t * 16 + c] = f2bf(en);
      }
    }
  }

  // ---- GEMM v = mem @ Wv ----
#pragma unroll
  for (int t = 0; t < 8; ++t) qa[t] = (f32x4){0.f, 0.f, 0.f, 0.f};
#pragma unroll
  for (int kk = 0; kk < 4; ++kk) {
    bf16x8 am = *(const bf16x8*)(Arow + 128 + kk * 32 + g * 8);
#pragma unroll
    for (int t = 0; t < 8; ++t) {
      bf16x8 b = *(const bf16x8*)(WvT + (size_t)(t * 16 + c) * 128 + kk * 32 + g * 8);
      qa[t] = __builtin_amdgcn_mfma_f32_16x16x32_bf16(am, b, qa[t], 0, 0, 0);
    }
  }
#pragma unroll
  for (int t = 0; t < 8; ++t)
#pragma unroll
    for (int rr = 0; rr < 4; ++rr)
      As[(r0 + g * 4 + rr) * AST2 + 128 + t * 16 + c] = f2bf(qa[t][rr]);  // v over mem

  // ---- coalesced stores: e_new (cols 256..) -> eb ; v (cols 128..) -> vb ----
#pragma unroll
  for (int it = 0; it < 4; ++it) {
    int row = it * 4 + g;
    size_t gr = (size_t)(e0 + r0 + row) * DD;
    *(uint4*)(eb + gr + c * 8) = *(const uint4*)(As + (r0 + row) * AST2 + 256 + c * 8);
    *(uint4*)(vb + gr + c * 8) = *(const uint4*)(As + (r0 + row) * AST2 + 128 + c * 8);
  }
}

// ---------- segment softmax ----------
__global__ __launch_bounds__(256) void k_segmax(
    const float* __restrict__ lg, const int* __restrict__ dst,
    unsigned* __restrict__ nmax) {
  int idx = blockIdx.x * 256 + threadIdx.x;
  int e = idx >> 3, h = idx & 7;
  float f = lg[idx];
  unsigned u = __float_as_uint(f);
  u = (u & 0x80000000u) ? ~u : (u | 0x80000000u);
  atomicMax(&nmax[dst[e] * 8 + h], u);
}

__global__ __launch_bounds__(256) void k_segexp(
    float* __restrict__ lg, const int* __restrict__ dst,
    const unsigned* __restrict__ nmax, float* __restrict__ nsum) {
  int idx = blockIdx.x * 256 + threadIdx.x;
  int e = idx >> 3, h = idx & 7;
  unsigned u = nmax[dst[e] * 8 + h];
  u = (u & 0x80000000u) ? (u ^ 0x80000000u) : ~u;
  float mx = __uint_as_float(u);
  float ex = expf(lg[idx] - mx);
  lg[idx] = ex;
  atomicAdd(&nsum[dst[e] * 8 + h], ex);
}

// ---------- attention aggregation (MFMA): agg[dst] += (attn*v) @ Wo ----------
__global__ __launch_bounds__(256) void k_attn(
    const ushort* __restrict__ vb, const float* __restrict__ exl,
    const float* __restrict__ nsum, const int* __restrict__ dst,
    const ushort* __restrict__ WoT, float* __restrict__ agg) {
  __shared__ __align__(16) ushort Vs[64 * 136];
  __shared__ float attnS[64 * 8];
  __shared__ int sD[64];
  const int tid = threadIdx.x;
  const int e0 = blockIdx.x * 64;
  if (tid < 64) sD[tid] = dst[e0 + tid];
  __syncthreads();
#pragma unroll
  for (int it = 0; it < 2; ++it) {
    int idx = it * 256 + tid;
    int er = idx >> 3, h = idx & 7;
    attnS[idx] = exl[(size_t)(e0 + er) * 8 + h] / (nsum[sD[er] * 8 + h] + 1e-16f);
  }
  __syncthreads();
#pragma unroll
  for (int it = 0; it < 4; ++it) {
    int ch = it * 256 + tid;        // 1024 chunks of 8 bf16
    int er = ch >> 4, j = ch & 15;
    uint4 vv = *(const uint4*)(vb + (size_t)(e0 + er) * DD + j * 8);
    float a = attnS[er * 8 + (j >> 1)];
    unsigned w[4] = {vv.x, vv.y, vv.z, vv.w};
    uint4 ov;
    unsigned r[4];
#pragma unroll
    for (int q = 0; q < 4; ++q) {
      ushort lo = f2bf(bf2f((ushort)(w[q] & 0xffff)) * a);
      ushort hi = f2bf(bf2f((ushort)(w[q] >> 16)) * a);
      r[q] = (unsigned)lo | ((unsigned)hi << 16);
    }
    ov.x = r[0]; ov.y = r[1]; ov.z = r[2]; ov.w = r[3];
    *(uint4*)(Vs + er * 136 + j * 8) = ov;
  }
  __syncthreads();
  const int lane = tid & 63, wv = tid >> 6;
  const int c = lane & 15, g = lane >> 4;
  const int r0 = wv * 16;
  const ushort* Arow = Vs + (r0 + c) * 136;
  f32x4 acc[8];
#pragma unroll
  for (int t = 0; t < 8; ++t) acc[t] = (f32x4){0.f, 0.f, 0.f, 0.f};
#pragma unroll
  for (int kk = 0; kk < 4; ++kk) {
    bf16x8 a = *(const bf16x8*)(Arow + kk * 32 + g * 8);
#pragma unroll
    for (int t = 0; t < 8; ++t) {
      bf16x8 b = *(const bf16x8*)(WoT + (size_t)(t * 16 + c) * 128 + kk * 32 + g * 8);
      acc[t] = __builtin_amdgcn_mfma_f32_16x16x32_bf16(a, b, acc[t], 0, 0, 0);
    }
  }
#pragma unroll
  for (int t = 0; t < 8; ++t)
#pragma unroll
    for (int rr = 0; rr < 4; ++rr) {
      int row = r0 + g * 4 + rr;
      atomicAdd(agg + (size_t)sD[row] * DD + t * 16 + c, acc[t][rr]);
    }
}

// ---------- x = ln(x + agg) ----------
__global__ __launch_bounds__(256) void k_nodeln(
    float* __restrict__ x, const float* __restrict__ agg,
    const float* __restrict__ g, const float* __restrict__ bt) {
  int row = blockIdx.x * 4 + (threadIdx.x >> 6);
  int lane = threadIdx.x & 63;
  size_t base = (size_t)row * DD;
  float a0 = x[base + lane] + agg[base + lane];
  float a1 = x[base + lane + 64] + agg[base + lane + 64];
  float m = wsum64(a0 + a1) * (1.0f / DD);
  float q = wsum64(a0 * a0 + a1 * a1) * (1.0f / DD);
  float rstd = rsqrtf(q - m * m + 1e-5f);
  x[base + lane] = (a0 - m) * rstd * g[lane] + bt[lane];
  x[base + lane + 64] = (a1 - m) * rstd * g[lane + 64] + bt[lane + 64];
}

// ---------- FFN ----------
__global__ __launch_bounds__(256) void k_ffn1(
    const float* __restrict__ x, const float* __restrict__ W1,
    const float* __restrict__ b1, float* __restrict__ h) {
  __shared__ float Xs[16 * 132];
  const int tid = threadIdx.x;
  const int r0 = blockIdx.x * 16;
#pragma unroll
  for (int i = 0; i < 2; ++i) {
    int f4 = i * 256 + tid;
    int r = f4 >> 5, k4 = f4 & 31;
    *(float4*)(Xs + r * 132 + k4 * 4) =
        *(const float4*)(x + (size_t)(r0 + r) * DD + k4 * 4);
  }
  __syncthreads();
  const int c = tid & 63, rg = tid >> 6;
  const int col = c * 4, rb = rg * 4;
  float acc[4][4];
#pragma unroll
  for (int j = 0; j < 4; ++j)
#pragma unroll
    for (int i = 0; i < 4; ++i) acc[j][i] = 0.0f;
#pragma unroll 4
  for (int k = 0; k < 128; ++k) {
    float4 w = *(const float4*)(W1 + k * 256 + col);
#pragma unroll
    for (int j = 0; j < 4; ++j) {
      float a = Xs[(rb + j) * 132 + k];
      acc[j][0] = fmaf(a, w.x, acc[j][0]);
      acc[j][1] = fmaf(a, w.y, acc[j][1]);
      acc[j][2] = fmaf(a, w.z, acc[j][2]);
      acc[j][3] = fmaf(a, w.w, acc[j][3]);
    }
  }
  float4 b = *(const float4*)(b1 + col);
#pragma unroll
  for (int j = 0; j < 4; ++j) {
    float4 o;
    o.x = fmaxf(acc[j][0] + b.x, 0.0f);
    o.y = fmaxf(acc[j][1] + b.y, 0.0f);
    o.z = fmaxf(acc[j][2] + b.z, 0.0f);
    o.w = fmaxf(acc[j][3] + b.w, 0.0f);
    *(float4*)(h + (size_t)(r0 + rb + j) * 256 + col) = o;
  }
}

__global__ __launch_bounds__(256) void k_ffn2(
    const float* __restrict__ x, const float* __restrict__ hb,
    const float* __restrict__ W2, const float* __restrict__ b2,
    const float* __restrict__ g, const float* __restrict__ bt,
    float* __restrict__ out, ushort* __restrict__ outB) {
  __shared__ float Hs[16 * 260];
  const int tid = threadIdx.x;
  const int r0 = blockIdx.x * 16;
#pragma unroll
  for (int i = 0; i < 4; ++i) {
    int f4 = i * 256 + tid;
    int r = f4 >> 6, k4 = f4 & 63;
    *(float4*)(Hs + r * 260 + k4 * 4) =
        *(const float4*)(hb + (size_t)(r0 + r) * 256 + k4 * 4);
  }
  __syncthreads();
  const int c = tid & 31, rg = tid >> 5;
  const int col = c * 4, rb = rg * 2;
  float acc[2][4];
#pragma unroll
  for (int j = 0; j < 2; ++j)
#pragma unroll
    for (int i = 0; i < 4; ++i) acc[j][i] = 0.0f;
#pragma unroll 4
  for (int k = 0; k < 256; ++k) {
    float4 w = *(const float4*)(W2 + k * DD + col);
#pragma unroll
    for (int j = 0; j < 2; ++j) {
      float a = Hs[(rb + j) * 260 + k];
      acc[j][0] = fmaf(a, w.x, acc[j][0]);
      acc[j][1] = fmaf(a, w.y, acc[j][1]);
      acc[j][2] = fmaf(a, w.z, acc[j][2]);
      acc[j][3] = fmaf(a, w.w, acc[j][3]);
    }
  }
  float4 b = *(const float4*)(b2 + col);
  float4 gg = *(const float4*)(g + col);
  float4 tt = *(const float4*)(bt + col);
#pragma unroll
  for (int j = 0; j < 2; ++j) {
    float4 xo = *(const float4*)(x + (size_t)(r0 + rb + j) * DD + col);
    float t0 = acc[j][0] + b.x + xo.x, t1 = acc[j][1] + b.y + xo.y;
    float t2 = acc[j][2] + b.z + xo.z, t3 = acc[j][3] + b.w + xo.w;
    float m = wsum32(t0 + t1 + t2 + t3) * (1.0f / DD);
    float q = wsum32(t0 * t0 + t1 * t1 + t2 * t2 + t3 * t3) * (1.0f / DD);
    float rstd = rsqrtf(q - m * m + 1e-5f);
    float4 o;
    o.x = (t0 - m) * rstd * gg.x + tt.x;
    o.y = (t1 - m) * rstd * gg.y + tt.y;
    o.z = (t2 - m) * rstd * gg.z + tt.z;
    o.w = (t3 - m) * rstd * gg.w + tt.w;
    *(float4*)(out + (size_t)(r0 + rb + j) * DD + col) = o;
    ushort4 ob;
    ob.x = f2bf(o.x); ob.y = f2bf(o.y); ob.z = f2bf(o.z); ob.w = f2bf(o.w);
    *(ushort4*)(outB + (size_t)(r0 + rb + j) * DD + col) = ob;
  }
}

extern "C" void kernel_launch(void* const* d_in, const int* in_sizes, int n_in,
                              void* d_out, int out_size, void* d_ws,
                              size_t ws_size, hipStream_t stream) {
  (void)in_sizes; (void)n_in; (void)out_size; (void)ws_size;
  const float* lane_feats = (const float*)d_in[0];
  const float* edge_attrs = (const float*)d_in[1];
  const int* ei = (const int*)d_in[2];
  const int* src = ei;
  const int* dst = ei + NE;
  const float* node_W = (const float*)d_in[3];
  const float* node_b = (const float*)d_in[4];
  const float* node_g = (const float*)d_in[5];
  const float* node_bt = (const float*)d_in[6];
  const float* rpe_W = (const float*)d_in[7];
  const float* rpe_b = (const float*)d_in[8];
  const float* rpe_g = (const float*)d_in[9];
  const float* rpe_bt = (const float*)d_in[10];
  const float* mem_W = (const float*)d_in[11];
  const float* mem_b = (const float*)d_in[12];
  const float* mem_g = (const float*)d_in[13];
  const float* mem_bt = (const float*)d_in[14];
  const float* Wq = (const float*)d_in[15];
  const float* Wk = (const float*)d_in[16];
  const float* Wv = (const float*)d_in[17];
  const float* Wo = (const float*)d_in[18];
  const float* eu_W = (const float*)d_in[19];
  const float* eu_b = (const float*)d_in[20];
  const float* eu_g = (const float*)d_in[21];
  const float* eu_bt = (const float*)d_in[22];
  const float* en_g = (const float*)d_in[23];
  const float* en_bt = (const float*)d_in[24];
  const float* ffn_W1 = (const float*)d_in[25];
  const float* ffn_b1 = (const float*)d_in[26];
  const float* ffn_W2 = (const float*)d_in[27];
  const float* ffn_b2 = (const float*)d_in[28];
  const float* n1_g = (const float*)d_in[29];
  const float* n1_bt = (const float*)d_in[30];
  const float* n2_g = (const float*)d_in[31];
  const float* n2_bt = (const float*)d_in[32];

  char* p = (char*)d_ws;
  auto alloc = [&](size_t bytes) -> char* {
    char* r = p; p += (bytes + 255) & ~(size_t)255; return r;
  };
  float* x = (float*)alloc((size_t)NN * DD * 4);
  float* agg = (float*)alloc((size_t)(NN * DD + NN * 16) * 4);  // + nmax + nsum
  float* nmaxF = agg + (size_t)NN * DD;
  float* nsum = nmaxF + (size_t)NN * 8;
  float* lg = (float*)alloc((size_t)NE * 8 * 4);
  float* hbuf = (float*)alloc((size_t)NN * 256 * 4);
  ushort* xb = (ushort*)alloc((size_t)NN * DD * 2);
  ushort* eb = (ushort*)alloc((size_t)NE * DD * 2);
  ushort* vb = (ushort*)alloc((size_t)NE * DD * 2);
  ushort* memWT = (ushort*)alloc((size_t)NL * 384 * DD * 2);
  ushort* euWT = (ushort*)alloc((size_t)NL * DD * DD * 2);
  ushort* WqT = (ushort*)alloc((size_t)NL * DD * DD * 2);
  ushort* WkT = (ushort*)alloc((size_t)NL * DD * DD * 2);
  ushort* WvT = (ushort*)alloc((size_t)NL * DD * DD * 2);
  ushort* WoT = (ushort*)alloc((size_t)NL * DD * DD * 2);

  // weight transposes (bf16)
  k_transp<<<dim3(12, 4, NL), 256, 0, stream>>>(mem_W, memWT, 384, DD);
  k_transp<<<dim3(4, 4, NL), 256, 0, stream>>>(eu_W, euWT, DD, DD);
  k_transp<<<dim3(4, 4, NL), 256, 0, stream>>>(Wq, WqT, DD, DD);
  k_transp<<<dim3(4, 4, NL), 256, 0, stream>>>(Wk, WkT, DD, DD);
  k_transp<<<dim3(4, 4, NL), 256, 0, stream>>>(Wv, WvT, DD, DD);
  k_transp<<<dim3(4, 4, NL), 256, 0, stream>>>(Wo, WoT, DD, DD);

  // input projections
  k_inproj<10><<<NN / 4, 256, 0, stream>>>(lane_feats, node_W, node_b, node_g,
                                           node_bt, x, xb, NN);
  k_inproj<9><<<NE / 4, 256, 0, stream>>>(edge_attrs, rpe_W, rpe_b, rpe_g,
                                          rpe_bt, nullptr, eb, NE);

  for (int l = 0; l < NL; ++l) {
    hipMemsetAsync(agg, 0, (size_t)(NN * DD + NN * 16) * sizeof(float), stream);
    k_edge<<<NE / 64, 256, 0, stream>>>(
        xb, eb, vb, src, dst, memWT + (size_t)l * 384 * DD, mem_b + l * DD,
        mem_g + l * DD, mem_bt + l * DD, euWT + (size_t)l * DD * DD,
        eu_b + l * DD, eu_g + l * DD, eu_bt + l * DD, en_g + l * DD,
        en_bt + l * DD, WqT + (size_t)l * DD * DD, WkT + (size_t)l * DD * DD,
        WvT + (size_t)l * DD * DD, lg);
    k_segmax<<<NE * 8 / 256, 256, 0, stream>>>(lg, dst, (unsigned*)nmaxF);
    k_segexp<<<NE * 8 / 256, 256, 0, stream>>>(lg, dst, (const unsigned*)nmaxF,
                                               nsum);
    k_attn<<<NE / 64, 256, 0, stream>>>(vb, lg, nsum, dst,
                                        WoT + (size_t)l * DD * DD, agg);
    k_nodeln<<<NN / 4, 256, 0, stream>>>(x, agg, n1_g + l * DD, n1_bt + l * DD);
    k_ffn1<<<NN / 16, 256, 0, stream>>>(x, ffn_W1 + (size_t)l * DD * 256,
                                        ffn_b1 + l * 256, hbuf);
    k_ffn2<<<NN / 16, 256, 0, stream>>>(
        x, hbuf, ffn_W2 + (size_t)l * 256 * DD, ffn_b2 + l * DD,
        n2_g + l * DD, n2_bt + l * DD, (l == NL - 1) ? (float*)d_out : x, xb);
  }
}